// Round 1
// 1329.865 us; speedup vs baseline: 1.9197x; 1.9197x over previous
//
#include <hip/hip_runtime.h>

#define T_SEQ 2048
#define DIN   16
#define HH    80
#define NTHR  512
#define NBLK  256
#define BT    2
#define ROWE  192   // f16 elems per row: [x 0:16 | h1 16:96 | h2 96:176 | pad]

#define L2E   1.44269504088896340736f

typedef _Float16 f16x8 __attribute__((ext_vector_type(8)));
typedef float    f32x4 __attribute__((ext_vector_type(4)));

__device__ __forceinline__ float rcp_fast(float x){ return __builtin_amdgcn_rcpf(x); }
__device__ __forceinline__ float ex2(float x){
#if __has_builtin(__builtin_amdgcn_exp2f)
    return __builtin_amdgcn_exp2f(x);
#else
    return exp2f(x);
#endif
}

#define MFMA16(ac, av, bv) ac = __builtin_amdgcn_mfma_f32_16x16x32_f16(av, bv, ac, 0, 0, 0)

__global__
__attribute__((amdgpu_flat_work_group_size(NTHR, NTHR)))
__attribute__((amdgpu_waves_per_eu(2, 2)))
void lstm2_mfma(
    const float* __restrict__ x,
    const float* __restrict__ W_ih1, const float* __restrict__ W_hh1,
    const float* __restrict__ b_ih1, const float* __restrict__ b_hh1,
    const float* __restrict__ W_ih2, const float* __restrict__ W_hh2,
    const float* __restrict__ b_ih2, const float* __restrict__ b_hh2,
    const float* __restrict__ W_d,   const float* __restrict__ b_d,
    float* __restrict__ out)
{
    __shared__ __align__(16) _Float16 HB[2][BT][ROWE];   // [parity][batch][row]

    const int t    = threadIdx.x;
    const int lane = t & 63;
    const int wv   = t >> 6;              // 0..7
    const bool isL1w = (wv < 4);          // waves 0-3: layer1, 4-7: layer2
    const int m16  = lane & 15;
    const int kgrp = lane >> 4;           // 0..3
    const int b0   = blockIdx.x * BT;

    const int uloc = isL1w ? 20*wv : 20*(wv-4);   // first unit of this wave's 5 tiles

    // ---------------- stationary A fragments (f16 weights, pre-scaled by log2 e) ----------------
    // A row m (=lane&15) within a tile: unit = base + (m>>2), gate = m&3  (i,f,g,o interleave)
    // A col k = 32*chunk + 8*kgrp + j   over concat-K: L1 = [x(16); h1(80)], L2 = [h1(80); h2(80)]
    f16x8 A[5][5];
    {
        const int g  = m16 & 3;
        const int ut = m16 >> 2;
        const float sc = (g == 2) ? (2.f*L2E) : L2E;     // tanh gate needs 2*log2e
        #pragma unroll
        for (int tl = 0; tl < 5; ++tl) {
            const int grow = g*HH + (uloc + 4*tl + ut);  // row in the 320-row weight matrices
            if (isL1w) {
                #pragma unroll
                for (int c = 0; c < 3; ++c) {
                    f16x8 a;
                    #pragma unroll
                    for (int j = 0; j < 8; ++j) {
                        const int k = 32*c + 8*kgrp + j;
                        const float v = (k < DIN) ? W_ih1[grow*DIN + k]
                                                  : W_hh1[grow*HH + (k - DIN)];
                        a[j] = (_Float16)(v * sc);
                    }
                    A[tl][c] = a;
                }
            } else {
                #pragma unroll
                for (int c = 0; c < 5; ++c) {
                    f16x8 a;
                    #pragma unroll
                    for (int j = 0; j < 8; ++j) {
                        const int k = 32*c + 8*kgrp + j;
                        const float v = (k < HH) ? W_ih2[grow*HH + k]
                                                 : W_hh2[grow*HH + (k - HH)];
                        a[j] = (_Float16)(v * sc);
                    }
                    A[tl][c] = a;
                }
            }
        }
    }

    // ---------------- merged-epilogue per-lane identity ----------------
    // C layout: col = lane&15 (batch col, replicated n&1), row = kgrp*4 + r (unit=kgrp, gate=r)
    // lane (m16=2*tl+b) already holds tile tl's correct batch column -> register select only.
    const int  tl_ep    = m16 >> 1;
    const bool act_ep   = (m16 < 10);
    const int  unit_ep  = uloc + 4*(act_ep ? tl_ep : 0) + kgrp;
    const int  batch_ep = lane & 1;
    const int  seg      = isL1w ? DIN : (DIN + HH);      // h1 at 16, h2 at 96
    const float* bI  = isL1w ? b_ih1 : b_ih2;
    const float* bHh = isL1w ? b_hh1 : b_hh2;
    const float bi = (bI[      unit_ep] + bHh[      unit_ep]) * L2E;
    const float bf = (bI[ 80 + unit_ep] + bHh[ 80 + unit_ep]) * L2E;
    const float bg = (bI[160 + unit_ep] + bHh[160 + unit_ep]) * (2.f*L2E);
    const float bo = (bI[240 + unit_ep] + bHh[240 + unit_ep]) * L2E;

    // ---------------- zero state, prime x pipeline (depth-3 prefetch) ----------------
    for (int i = t; i < 2*BT*ROWE; i += NTHR) ((_Float16*)HB)[i] = (_Float16)0.f;
    __syncthreads();

    const int xbn = (lane >> 4) & 1;
    const int xch = lane & 15;
    const float* xptr = x + ((size_t)(b0 + xbn) * T_SEQ) * DIN + xch;
    float xa = 0.f, xbv = 0.f, xcv = 0.f;
    if (wv == 0 && lane < 32) {
        HB[0][xbn][xch] = (_Float16)xptr[0];
        xa  = xptr[1*DIN];
        xbv = xptr[2*DIN];
        xcv = xptr[3*DIN];
    }
    __syncthreads();

    float cst = 0.f;   // cell state for this lane's (unit,batch) pair

    // iter k: L1 computes h1(k) from [x(k),h1(k-1)] in pb; L2 computes h2(k-1)
    // from [h1(k-1),h2(k-2)] in pb. Both write parity nb.
    #pragma unroll 1
    for (int k = 0; k <= T_SEQ; ++k) {
        const int pb = k & 1, nb = pb ^ 1;

        if (wv == 0 && lane < 32) {          // stage x(k+1) -> nb; refill 3 iters ahead
            HB[nb][xbn][xch] = (_Float16)xa;
            xa = xbv; xbv = xcv;
            const int tn = (k + 4 < T_SEQ) ? (k + 4) : (T_SEQ - 1);
            xcv = xptr[(size_t)tn * DIN];
        }

        const bool act = isL1w ? (k < T_SEQ) : (k >= 1);
        if (act) {
            const _Float16* rb = &HB[pb][lane & 1][0];   // B col n <- batch n&1 (replicated)
            f32x4 acc0 = {0.f,0.f,0.f,0.f}, acc1 = {0.f,0.f,0.f,0.f},
                  acc2 = {0.f,0.f,0.f,0.f}, acc3 = {0.f,0.f,0.f,0.f},
                  acc4 = {0.f,0.f,0.f,0.f};

            if (isL1w) {
                const f16x8 B0 = *(const f16x8*)(rb +       8*kgrp);
                const f16x8 B1 = *(const f16x8*)(rb +  32 + 8*kgrp);
                const f16x8 B2 = *(const f16x8*)(rb +  64 + 8*kgrp);
                MFMA16(acc0, A[0][0], B0); MFMA16(acc0, A[0][1], B1); MFMA16(acc0, A[0][2], B2);
                MFMA16(acc1, A[1][0], B0); MFMA16(acc1, A[1][1], B1); MFMA16(acc1, A[1][2], B2);
                MFMA16(acc2, A[2][0], B0); MFMA16(acc2, A[2][1], B1); MFMA16(acc2, A[2][2], B2);
                MFMA16(acc3, A[3][0], B0); MFMA16(acc3, A[3][1], B1); MFMA16(acc3, A[3][2], B2);
                MFMA16(acc4, A[4][0], B0); MFMA16(acc4, A[4][1], B1); MFMA16(acc4, A[4][2], B2);
            } else {
                const f16x8 B0 = *(const f16x8*)(rb +  16 + 8*kgrp);
                const f16x8 B1 = *(const f16x8*)(rb +  48 + 8*kgrp);
                const f16x8 B2 = *(const f16x8*)(rb +  80 + 8*kgrp);
                const f16x8 B3 = *(const f16x8*)(rb + 112 + 8*kgrp);
                const f16x8 B4 = *(const f16x8*)(rb + 144 + 8*kgrp);
                MFMA16(acc0, A[0][0], B0); MFMA16(acc0, A[0][1], B1); MFMA16(acc0, A[0][2], B2);
                MFMA16(acc0, A[0][3], B3); MFMA16(acc0, A[0][4], B4);
                MFMA16(acc1, A[1][0], B0); MFMA16(acc1, A[1][1], B1); MFMA16(acc1, A[1][2], B2);
                MFMA16(acc1, A[1][3], B3); MFMA16(acc1, A[1][4], B4);
                MFMA16(acc2, A[2][0], B0); MFMA16(acc2, A[2][1], B1); MFMA16(acc2, A[2][2], B2);
                MFMA16(acc2, A[2][3], B3); MFMA16(acc2, A[2][4], B4);
                MFMA16(acc3, A[3][0], B0); MFMA16(acc3, A[3][1], B1); MFMA16(acc3, A[3][2], B2);
                MFMA16(acc3, A[3][3], B3); MFMA16(acc3, A[3][4], B4);
                MFMA16(acc4, A[4][0], B0); MFMA16(acc4, A[4][1], B1); MFMA16(acc4, A[4][2], B2);
                MFMA16(acc4, A[4][3], B3); MFMA16(acc4, A[4][4], B4);
            }

            // in-register merge: pick own tile's (i,f,g,o) — pure cndmask chain
            float M0 = acc0[0], M1 = acc0[1], M2 = acc0[2], M3 = acc0[3];
            if (tl_ep == 1) { M0 = acc1[0]; M1 = acc1[1]; M2 = acc1[2]; M3 = acc1[3]; }
            if (tl_ep == 2) { M0 = acc2[0]; M1 = acc2[1]; M2 = acc2[2]; M3 = acc2[3]; }
            if (tl_ep == 3) { M0 = acc3[0]; M1 = acc3[1]; M2 = acc3[2]; M3 = acc3[3]; }
            if (tl_ep == 4) { M0 = acc4[0]; M1 = acc4[1]; M2 = acc4[2]; M3 = acc4[3]; }

            // activations (pre-acts already scaled by log2e / 2*log2e)
            const float gi = M0 + bi, gf = M1 + bf, gg = M2 + bg, go = M3 + bo;
            const float iv = rcp_fast(1.f + ex2(-gi));
            const float fv = rcp_fast(1.f + ex2(-gf));
            const float ov = rcp_fast(1.f + ex2(-go));
            const float gv = 1.f - 2.f*rcp_fast(1.f + ex2(gg));
            cst = fv*cst + iv*gv;
            const float tc = 1.f - 2.f*rcp_fast(1.f + ex2(cst * (2.f*L2E)));
            if (act_ep) HB[nb][batch_ep][seg + unit_ep] = (_Float16)(ov * tc);
        }
        __syncthreads();
    }

    // ---------------- dense head: out[b] = W_d . h2(T-1) + b_d ; final h2 in parity 1 ----------------
    if (wv == 0) {
        float a0 = 0.f, a1 = 0.f;
        for (int u = lane; u < HH; u += 64) {
            const float wd = W_d[u];
            a0 += wd * (float)HB[1][0][DIN + HH + u];
            a1 += wd * (float)HB[1][1][DIN + HH + u];
        }
        #pragma unroll
        for (int off = 32; off > 0; off >>= 1) {
            a0 += __shfl_down(a0, off);
            a1 += __shfl_down(a1, off);
        }
        if (lane == 0) { out[b0] = a0 + b_d[0]; out[b0 + 1] = a1 + b_d[0]; }
    }
}

extern "C" void kernel_launch(void* const* d_in, const int* in_sizes, int n_in,
                              void* d_out, int out_size, void* d_ws, size_t ws_size,
                              hipStream_t stream) {
    const float* x     = (const float*)d_in[0];
    const float* W_ih1 = (const float*)d_in[1];
    const float* W_hh1 = (const float*)d_in[2];
    const float* b_ih1 = (const float*)d_in[3];
    const float* b_hh1 = (const float*)d_in[4];
    const float* W_ih2 = (const float*)d_in[5];
    const float* W_hh2 = (const float*)d_in[6];
    const float* b_ih2 = (const float*)d_in[7];
    const float* b_hh2 = (const float*)d_in[8];
    const float* W_d   = (const float*)d_in[9];
    const float* b_d   = (const float*)d_in[10];

    lstm2_mfma<<<NBLK, NTHR, 0, stream>>>(x, W_ih1, W_hh1, b_ih1, b_hh1,
                                          W_ih2, W_hh2, b_ih2, b_hh2,
                                          W_d, b_d, (float*)d_out);
}